// Round 8
// baseline (376.451 us; speedup 1.0000x reference)
//
#include <hip/hip_runtime.h>

#define NAGENTS 8
#define NM 128          // NAGENTS*MITEMS
#define MENU 256
#define SFULL 257       // MENU + null entry

typedef float f32x4 __attribute__((ext_vector_type(4)));

// Raw barrier: wait LDS ops only (no vmcnt drain — copy-out stores and any
// in-flight loads keep flying across phases).
#define BAR() asm volatile("s_waitcnt lgkmcnt(0)\n\ts_barrier" ::: "memory")

__device__ __forceinline__ float wredmax(float v) {
#pragma unroll
    for (int o = 32; o; o >>= 1) v = fmaxf(v, __shfl_xor(v, o));
    return v;
}
__device__ __forceinline__ float wredsum(float v) {
#pragma unroll
    for (int o = 32; o; o >>= 1) v += __shfl_xor(v, o);
    return v;
}

// 256 threads/block, one auction per block. Payload streamed ONCE with
// nontemporal load/store (touch-once data; keep L2 out of the way), batched
// 4 loads -> 4 stores -> compute to pin R/W run lengths. Online-softmax
// (flash-style) folds item_allocation into the single pass. launch_bounds
// (256,6) gives the allocator ~85 VGPRs so the hot loop cannot spill.
__global__ __launch_bounds__(256, 6) void cama_kernel(
    const float* __restrict__ bids,   // B,8,16
    const float* __restrict__ allocs, // B,256,8,16
    const float* __restrict__ wvec,   // B,8
    const float* __restrict__ bvec,   // B,256
    const float* __restrict__ tempp,  // 1
    float* __restrict__ out, int Bsz)
{
    __shared__ float lds_pwT[NAGENTS * MENU];        // 8KB, [n][s^(n<<2)]
    __shared__ float lds_tot[MENU];                  // 1KB
    __shared__ float lds_bb[MENU];                   // 1KB
    __shared__ float lds_ch[SFULL];
    __shared__ __align__(16) float4 lds_accs[4][32]; // 2KB online-acc merge
    __shared__ __align__(8)  float2 lds_mz[4][32];   // 1KB (m, Z) merge
    __shared__ float lds_rcs[NAGENTS], lds_rb[NAGENTS], lds_cw[NAGENTS];
    __shared__ float lds_ab;

    const int u = threadIdx.x;    // 0..255
    const int lane = u & 63;
    const int wave = u >> 6;      // 0..3
    const int c = u & 31;         // float4 column: n = c>>2, item-quad = c&3
    const int n = c >> 2;
    const int su = u >> 5;        // 0..7: row subset (s = 8k + su)
    const size_t bb_ = (size_t)blockIdx.x;

    float* out_choice = out;                                  // B*257
    float* out_item   = out + (size_t)Bsz * SFULL;            // B*128
    float* out_pay    = out_item + (size_t)Bsz * NM;          // 8*B
    float* out_all    = out_pay + (size_t)NAGENTS * Bsz;      // B*257*128
    f32x4* out_all4   = (f32x4*)out_all + bb_ * 8224;
    const f32x4* src4 = (const f32x4*)allocs + bb_ * 8192;

    const float temp = tempp[0];
    lds_bb[u] = bvec[bb_ * MENU + u];                    // stage b (256 = blockDim)
    const float4 q4 = ((const float4*)(bids + bb_ * NM))[c];   // L1 broadcast
    const float w_n = wvec[bb_ * NAGENTS + n];
    BAR();   // bb staged

    // ---- pass 1: single streaming pass over the payload ----
    float m_r = -1e30f, Z_r = 0.f;
    float4 acc = make_float4(0.f, 0.f, 0.f, 0.f);
#pragma unroll
    for (int g = 0; g < 8; ++g) {
        f32x4 buf[4];
#pragma unroll
        for (int j = 0; j < 4; ++j)
            buf[j] = __builtin_nontemporal_load(&src4[(((g << 2) + j) << 8) + u]);
#pragma unroll
        for (int j = 0; j < 4; ++j)
            __builtin_nontemporal_store(buf[j], &out_all4[(((g << 2) + j) << 8) + u]);
#pragma unroll
        for (int j = 0; j < 4; ++j) {
            const int s = (((g << 2) + j) << 3) + su;
            float util = buf[j][0]*q4.x + buf[j][1]*q4.y
                       + buf[j][2]*q4.z + buf[j][3]*q4.w;
            util += __shfl_xor(util, 1);
            util += __shfl_xor(util, 2);           // full item-dot for (s,n)
            float pwv = w_n * util;
            if ((u & 3) == 0) lds_pwT[(n << 8) + (s ^ (n << 2))] = pwv;
            float t = pwv;
            t += __shfl_xor(t, 4);
            t += __shfl_xor(t, 8);
            t += __shfl_xor(t, 16);                // total welfare, all lanes
            if (c == 0) lds_tot[s] = t;
            // online softmax accumulate for item_allocation
            float x = (t + lds_bb[s]) * temp;
            float mn = fmaxf(m_r, x);
            float sc = __expf(m_r - mn);           // 1.0 when no new max
            float p  = __expf(x - mn);
            Z_r = Z_r * sc + p;
            acc.x = acc.x * sc + p * buf[j][0];
            acc.y = acc.y * sc + p * buf[j][1];
            acc.z = acc.z * sc + p * buf[j][2];
            acc.w = acc.w * sc + p * buf[j][3];
            m_r = mn;
        }
    }
    if (u < 32) {
        f32x4 z4 = {0.f, 0.f, 0.f, 0.f};
        __builtin_nontemporal_store(z4, &out_all4[8192 + u]);   // null row
    }

    // pair-merge su <-> su^1 (halves of each wave)
    {
        float mo = __shfl_xor(m_r, 32);
        float Zo = __shfl_xor(Z_r, 32);
        float ax = __shfl_xor(acc.x, 32), ay = __shfl_xor(acc.y, 32);
        float az = __shfl_xor(acc.z, 32), aw = __shfl_xor(acc.w, 32);
        float mn = fmaxf(m_r, mo);
        float s0 = __expf(m_r - mn), s1 = __expf(mo - mn);
        Z_r = Z_r * s0 + Zo * s1;
        acc.x = acc.x * s0 + ax * s1;
        acc.y = acc.y * s0 + ay * s1;
        acc.z = acc.z * s0 + az * s1;
        acc.w = acc.w * s0 + aw * s1;
        if (lane < 32) {
            lds_accs[wave][c] = acc;
            lds_mz[wave][c] = make_float2(mn, Z_r);
        }
    }
    BAR();   // b1: pwT/tot/accs ready

    // ---- softmax tasks: t=0 full, t=1..8 leave-one-out (i=t-1); 4 waves ----
    for (int t = wave; t < 9; t += 4) {
        if (t == 0) {
            float xs[4], bl[4], es[4];
            float mx = -1e30f;
#pragma unroll
            for (int c4 = 0; c4 < 4; ++c4) {
                int v = (c4 << 6) | lane;
                bl[c4] = lds_bb[v];
                float x = (lds_tot[v] + bl[c4]) * temp;
                xs[c4] = x; mx = fmaxf(mx, x);
            }
            mx = fmaxf(wredmax(mx), 0.f);          // null entry x=0
            float se = 0.f, sab = 0.f;
#pragma unroll
            for (int c4 = 0; c4 < 4; ++c4) {
                es[c4] = __expf(xs[c4] - mx);
                se += es[c4]; sab += es[c4] * bl[c4];
            }
            float en = __expf(-mx);
            se = wredsum(se) + en;
            sab = wredsum(sab);
            float inv = 1.f / se;
#pragma unroll
            for (int c4 = 0; c4 < 4; ++c4) {
                int v = (c4 << 6) | lane;
                float chv = es[c4] * inv;
                lds_ch[v] = chv;
                out_choice[bb_ * SFULL + v] = chv;
            }
            if (lane == 0) {
                float chn = en * inv;
                lds_ch[MENU] = chn;
                out_choice[bb_ * SFULL + MENU] = chn;
                lds_ab = sab * inv;
            }
        } else {
            const int i = t - 1;
            float xs[4], trs[4], bl[4];
            float mx = -1e30f;
#pragma unroll
            for (int c4 = 0; c4 < 4; ++c4) {
                int v = (c4 << 6) | lane;
                bl[c4] = lds_bb[v];
                float tr = lds_tot[v] - lds_pwT[(i << 8) + (v ^ (i << 2))];
                trs[c4] = tr;
                float x = (tr + bl[c4]) * temp;
                xs[c4] = x; mx = fmaxf(mx, x);
            }
            mx = fmaxf(wredmax(mx), 0.f);
            float se = 0.f, s1 = 0.f, s2 = 0.f;
#pragma unroll
            for (int c4 = 0; c4 < 4; ++c4) {
                float e = __expf(xs[c4] - mx);
                se += e; s1 += e * trs[c4]; s2 += e * bl[c4];
            }
            se = wredsum(se) + __expf(-mx);
            s1 = wredsum(s1);
            s2 = wredsum(s2);
            if (lane == 0) { lds_rcs[i] = s1 / se; lds_rb[i] = s2 / se; }
        }
    }
    BAR();   // b2: ch/rcs/rb/ab ready

    // ---- chosen welfare (2 agents per wave) ----
    for (int i = wave; i < NAGENTS; i += 4) {
        float cwv = 0.f;
#pragma unroll
        for (int c4 = 0; c4 < 4; ++c4) {
            int v = (c4 << 6) | lane;
            cwv += lds_ch[v] * lds_pwT[(i << 8) + (v ^ (i << 2))];
        }
        cwv = wredsum(cwv);
        if (lane == 0) lds_cw[i] = cwv;
    }
    // ---- item_allocation: final cross-wave merge + null + normalize ----
    if (u < 32) {
        float4 A = lds_accs[0][u];
        float2 mz = lds_mz[0][u];
        float M = mz.x, Z = mz.y;
#pragma unroll
        for (int j = 1; j < 4; ++j) {
            float4 Aj = lds_accs[j][u];
            float2 mzj = lds_mz[j][u];
            float mn = fmaxf(M, mzj.x);
            float s0 = __expf(M - mn), s1 = __expf(mzj.x - mn);
            Z = Z * s0 + mzj.y * s1;
            A.x = A.x * s0 + Aj.x * s1;
            A.y = A.y * s0 + Aj.y * s1;
            A.z = A.z * s0 + Aj.z * s1;
            A.w = A.w * s0 + Aj.w * s1;
            M = mn;
        }
        float mn = fmaxf(M, 0.f);                  // null entry
        float s0 = __expf(M - mn);
        Z = Z * s0 + __expf(-mn);
        float inv = 1.f / Z;
        s0 *= inv;
        ((float4*)(out_item + bb_ * NM))[u] =
            make_float4(A.x * s0, A.y * s0, A.z * s0, A.w * s0);
    }
    BAR();   // b3: cw ready

    // ---- payments, layout (n, B) ----
    if (u < NAGENTS) {
        float ctot = 0.f;
#pragma unroll
        for (int k = 0; k < NAGENTS; ++k) ctot += lds_cw[k];
        float pay = (lds_rcs[u] + lds_rb[u] - (ctot - lds_cw[u]) - lds_ab)
                    / wvec[bb_ * NAGENTS + u];
        out_pay[(size_t)u * Bsz + bb_] = pay;
    }
}

extern "C" void kernel_launch(void* const* d_in, const int* in_sizes, int n_in,
                              void* d_out, int out_size, void* d_ws, size_t ws_size,
                              hipStream_t stream) {
    const float* bids   = (const float*)d_in[0];
    const float* allocs = (const float*)d_in[1];
    const float* wvec   = (const float*)d_in[2];
    const float* bvec   = (const float*)d_in[3];
    const float* tempp  = (const float*)d_in[4];
    float* out = (float*)d_out;
    const int Bsz = in_sizes[0] / NM;          // 4096
    cama_kernel<<<Bsz, 256, 0, stream>>>(bids, allocs, wvec, bvec, tempp,
                                         out, Bsz);
}